// Round 5
// baseline (590.242 us; speedup 1.0000x reference)
//
#include <hip/hip_runtime.h>
#include <math.h>

#define EMB 1024
#define HEADS 16
#define DH 64
#define DFF 4096
#define NTOK 2048
#define BATCH 2
#define MROWS 4096

typedef __attribute__((ext_vector_type(8))) _Float16 f16x8;
typedef __attribute__((ext_vector_type(4))) float floatx4;

typedef const __attribute__((address_space(1))) void gas_void;
typedef __attribute__((address_space(3))) void las_void;

__device__ __forceinline__ unsigned short f2h(float f) {
    union { _Float16 h; unsigned short u; } c; c.h = (_Float16)f; return c.u;
}
__device__ __forceinline__ float h2f(unsigned short u) {
    union { _Float16 h; unsigned short u; } c; c.u = u; return (float)c.h;
}

// ---------------- bias concat fp32: [bq|bk|bv | b1 | b2] = 3072+4096+1024 ----
__global__ __launch_bounds__(256) void bias_prep(
    const float* __restrict__ bq, const float* __restrict__ bk,
    const float* __restrict__ bv, const float* __restrict__ b1,
    const float* __restrict__ b2, float* __restrict__ out)
{
    int i = blockIdx.x * 256 + threadIdx.x;
    float v;
    if (i < 1024)      v = bq[i];
    else if (i < 2048) v = bk[i - 1024];
    else if (i < 3072) v = bv[i - 2048];
    else if (i < 7168) v = b1[i - 3072];
    else               v = b2[i - 7168];
    out[i] = v;
}

// ---------------- transpose fp32 -> fp16: out[c][r] = in[r][c], 64x64 tiles ----
__global__ __launch_bounds__(256) void transpose_f2h(
    const float* __restrict__ in, int ld_in,
    unsigned short* __restrict__ out, int ld_out)
{
    __shared__ unsigned short tile[64][72];
    const int t = threadIdx.x;
    const int r0 = blockIdx.y * 64, c0 = blockIdx.x * 64;
    const int rr = t >> 4, c4 = (t & 15) * 4;
#pragma unroll
    for (int p = 0; p < 4; p++) {
        float4 v = *(const float4*)&in[(size_t)(r0 + rr + p * 16) * ld_in + c0 + c4];
        tile[rr + p * 16][c4 + 0] = f2h(v.x);
        tile[rr + p * 16][c4 + 1] = f2h(v.y);
        tile[rr + p * 16][c4 + 2] = f2h(v.z);
        tile[rr + p * 16][c4 + 3] = f2h(v.w);
    }
    __syncthreads();
#pragma unroll
    for (int p = 0; p < 4; p++) {
        const int c = rr + p * 16;
        ushort4 v;
        v.x = tile[c4 + 0][c]; v.y = tile[c4 + 1][c];
        v.z = tile[c4 + 2][c]; v.w = tile[c4 + 3][c];
        *(ushort4*)&out[(size_t)(c0 + c) * ld_out + r0 + c4] = v;
    }
}

// ---------------- V transpose (fp16): vT[bh][d][n] = qkv[b*NTOK+n][2048+h*64+d] ----
__global__ __launch_bounds__(256) void vtrans(
    const unsigned short* __restrict__ qkv, unsigned short* __restrict__ vT)
{
    __shared__ unsigned short tile[64][72];
    const int t = threadIdx.x;
    const int n0 = blockIdx.x * 64;
    const int bh = blockIdx.y;
    const int b = bh >> 4, h = bh & 15;
    const int rr = t >> 4, c4 = (t & 15) * 4;
    const unsigned short* src = qkv + (size_t)b * NTOK * 3072 + 2048 + h * 64;
#pragma unroll
    for (int p = 0; p < 4; p++) {
        ushort4 v = *(const ushort4*)&src[(size_t)(n0 + rr + p * 16) * 3072 + c4];
        *(ushort4*)&tile[rr + p * 16][c4] = v;
    }
    __syncthreads();
    unsigned short* dst = vT + (size_t)bh * 64 * NTOK;
#pragma unroll
    for (int p = 0; p < 4; p++) {
        const int d = rr + p * 16;
        ushort4 v;
        v.x = tile[c4 + 0][d]; v.y = tile[c4 + 1][d];
        v.z = tile[c4 + 2][d]; v.w = tile[c4 + 3][d];
        *(ushort4*)&dst[(size_t)d * NTOK + n0 + c4] = v;
    }
}

// ---------------- LayerNorm: fp32 in -> fp16 out, rows of 1024 ----
__global__ __launch_bounds__(256) void ln_kernel(
    const float* __restrict__ in,
    const float* __restrict__ g,
    const float* __restrict__ be,
    unsigned short* __restrict__ out)
{
    const int row = blockIdx.x, t = threadIdx.x;
    const size_t base = (size_t)row * 1024 + t * 4;
    float4 xv = *(const float4*)&in[base];
    float v0 = xv.x, v1 = xv.y, v2 = xv.z, v3 = xv.w;
    float s = v0 + v1 + v2 + v3;
    float q = v0 * v0 + v1 * v1 + v2 * v2 + v3 * v3;
#pragma unroll
    for (int m = 1; m < 64; m <<= 1) { s += __shfl_xor(s, m, 64); q += __shfl_xor(q, m, 64); }
    __shared__ float red[8];
    if ((t & 63) == 0) { red[t >> 6] = s; red[4 + (t >> 6)] = q; }
    __syncthreads();
    s = red[0] + red[1] + red[2] + red[3];
    q = red[4] + red[5] + red[6] + red[7];
    const float mu = s * (1.f / 1024.f);
    const float var = q * (1.f / 1024.f) - mu * mu;
    const float rs = rsqrtf(var + 1e-6f);
    float4 gv = *(const float4*)&g[t * 4];
    float4 bv = *(const float4*)&be[t * 4];
    ushort4 ov;
    ov.x = f2h((v0 - mu) * rs * gv.x + bv.x);
    ov.y = f2h((v1 - mu) * rs * gv.y + bv.y);
    ov.z = f2h((v2 - mu) * rs * gv.z + bv.z);
    ov.w = f2h((v3 - mu) * rs * gv.w + bv.w);
    *(ushort4*)&out[base] = ov;
}

// ---------------- GEMM: C = A[M][K] @ Bt[N][K]^T + bias, epilogue EPI ----
// EPI 0: fp16 store. 1: exact GELU, fp16 store. 2: + fp32 resid, fp32 store.
// 128x128 tile, BK=64, 4 waves (2x2), 4x4 16x16x32-MFMA frags/wave (m97 structure)
template<int EPI, typename CT>
__global__ __launch_bounds__(256) void gemm_f16(
    const unsigned short* __restrict__ A, int lda,
    const unsigned short* __restrict__ Bt, int ldb,
    const float* __restrict__ bias,
    const float* __restrict__ resid,
    CT* __restrict__ C, int ldc, int K)
{
    __shared__ unsigned short As[128 * 64];
    __shared__ unsigned short Bs[128 * 64];
    const int t = threadIdx.x;
    const int l = t & 63, w = t >> 6;
    const int wr = w >> 1, wc = w & 1;
    const int lr = l & 15, lg = l >> 4;
    const int m0 = blockIdx.y * 128, n0 = blockIdx.x * 128;

    const int srow = t >> 3;        // 0..31
    const int scol = (t & 7) * 8;   // 0..56
    const unsigned short* ga0 = A + (size_t)(m0 + srow) * lda + scol;
    const unsigned short* gb0 = Bt + (size_t)(n0 + srow) * ldb + scol;
    const int ldsbase = w * 512;    // element offset, wave-uniform

    floatx4 acc[4][4];
#pragma unroll
    for (int a = 0; a < 4; a++)
#pragma unroll
        for (int b = 0; b < 4; b++) acc[a][b] = (floatx4){0.f, 0.f, 0.f, 0.f};

    for (int k0 = 0; k0 < K; k0 += 64) {
#pragma unroll
        for (int i = 0; i < 4; i++)
            __builtin_amdgcn_global_load_lds((gas_void*)(ga0 + (size_t)i * 32 * lda + k0),
                                             (las_void*)(As + i * 2048 + ldsbase), 16, 0, 0);
#pragma unroll
        for (int i = 0; i < 4; i++)
            __builtin_amdgcn_global_load_lds((gas_void*)(gb0 + (size_t)i * 32 * ldb + k0),
                                             (las_void*)(Bs + i * 2048 + ldsbase), 16, 0, 0);
        __syncthreads();
#pragma unroll
        for (int kf = 0; kf < 2; kf++) {
            f16x8 af[4], bfr[4];
#pragma unroll
            for (int a = 0; a < 4; a++)
                af[a] = *(const f16x8*)&As[(wr * 64 + a * 16 + lr) * 64 + kf * 32 + lg * 8];
#pragma unroll
            for (int b = 0; b < 4; b++)
                bfr[b] = *(const f16x8*)&Bs[(wc * 64 + b * 16 + lr) * 64 + kf * 32 + lg * 8];
#pragma unroll
            for (int a = 0; a < 4; a++)
#pragma unroll
                for (int b = 0; b < 4; b++)
                    acc[a][b] = __builtin_amdgcn_mfma_f32_16x16x32_f16(af[a], bfr[b], acc[a][b], 0, 0, 0);
        }
        __syncthreads();
    }

#pragma unroll
    for (int a = 0; a < 4; a++) {
        const int row0 = m0 + wr * 64 + a * 16 + lg * 4;
#pragma unroll
        for (int b = 0; b < 4; b++) {
            const int col = n0 + wc * 64 + b * 16 + lr;
            const float bs = bias[col];
#pragma unroll
            for (int r = 0; r < 4; r++) {
                float v = acc[a][b][r] + bs;
                if (EPI == 1) v = 0.5f * v * (1.0f + erff(v * 0.70710678118654752f));
                const size_t idx = (size_t)(row0 + r) * ldc + col;
                if (EPI == 2) v += resid[idx];
                if (sizeof(CT) == 2) C[idx] = (CT)f2h(v);
                else                 C[idx] = (CT)v;
            }
        }
    }
}

// ---------------- Flash attention v2 (no 1/sqrt(dh) scale!), residual fused ----
// grid (32 qblocks, 32 bh); 4 waves x 16 q-rows each = 64 rows/block; KVBLK=64.
// K/V direct from global (L2-resident); P bounced via padded LDS [16][72].
__global__ __launch_bounds__(256, 4) void attn_kernel(
    const unsigned short* __restrict__ qkv,
    const unsigned short* __restrict__ vT,
    const float* __restrict__ x,
    float* __restrict__ y)
{
    __shared__ unsigned short P[4][16 * 72];
    const int t = threadIdx.x;
    const int l = t & 63, w = t >> 6;
    const int lr = l & 15, lg = l >> 4;
    const int qb = blockIdx.x, bh = blockIdx.y;
    const int b = bh >> 4, h = bh & 15;
    const int q0 = qb * 64 + w * 16;   // qb in [0,32) -> q0 in [0, 2032]

    const unsigned short* qbase = qkv + (size_t)b * NTOK * 3072 + h * 64;
    const unsigned short* kbase = qbase + 1024;
    const unsigned short* vbase = vT + (size_t)bh * 64 * NTOK;

    f16x8 qf[2];
#pragma unroll
    for (int kf = 0; kf < 2; kf++)
        qf[kf] = *(const f16x8*)&qbase[(size_t)(q0 + lr) * 3072 + kf * 32 + lg * 8];

    floatx4 o[4];
    float mrun[4], lrun[4];
#pragma unroll
    for (int df = 0; df < 4; df++) o[df] = (floatx4){0.f, 0.f, 0.f, 0.f};
#pragma unroll
    for (int r = 0; r < 4; r++) { mrun[r] = -1e30f; lrun[r] = 0.f; }

    for (int kt = 0; kt < NTOK; kt += 64) {
        // QK^T: s[n][r] = score(q = q0+lg*4+r, key = kt+n*16+lr)
        floatx4 s[4];
#pragma unroll
        for (int n = 0; n < 4; n++) {
            f16x8 k0 = *(const f16x8*)&kbase[(size_t)(kt + n * 16 + lr) * 3072 + lg * 8];
            f16x8 k1 = *(const f16x8*)&kbase[(size_t)(kt + n * 16 + lr) * 3072 + 32 + lg * 8];
            s[n] = (floatx4){0.f, 0.f, 0.f, 0.f};
            s[n] = __builtin_amdgcn_mfma_f32_16x16x32_f16(qf[0], k0, s[n], 0, 0, 0);
            s[n] = __builtin_amdgcn_mfma_f32_16x16x32_f16(qf[1], k1, s[n], 0, 0, 0);
        }

        // online softmax over 64 keys; row r lives in lanes sharing lg
#pragma unroll
        for (int r = 0; r < 4; r++) {
            float tm = fmaxf(fmaxf(s[0][r], s[1][r]), fmaxf(s[2][r], s[3][r]));
#pragma unroll
            for (int msk = 1; msk < 16; msk <<= 1) tm = fmaxf(tm, __shfl_xor(tm, msk, 64));
            const float nm = fmaxf(mrun[r], tm);
            const float corr = __expf(mrun[r] - nm);
            mrun[r] = nm;
            float p0 = __expf(s[0][r] - nm);
            float p1 = __expf(s[1][r] - nm);
            float p2 = __expf(s[2][r] - nm);
            float p3 = __expf(s[3][r] - nm);
            float rs = (p0 + p1) + (p2 + p3);
#pragma unroll
            for (int msk = 1; msk < 16; msk <<= 1) rs += __shfl_xor(rs, msk, 64);
            lrun[r] = lrun[r] * corr + rs;
#pragma unroll
            for (int df = 0; df < 4; df++) o[df][r] *= corr;
            const int prow = (lg * 4 + r) * 72;
            P[w][prow + lr]      = f2h(p0);
            P[w][prow + 16 + lr] = f2h(p1);
            P[w][prow + 32 + lr] = f2h(p2);
            P[w][prow + 48 + lr] = f2h(p3);
        }

        // PV: A = P[q][key] from LDS, B = vT (key contiguous)
        f16x8 pa0 = *(const f16x8*)&P[w][lr * 72 + lg * 8];
        f16x8 pa1 = *(const f16x8*)&P[w][lr * 72 + 32 + lg * 8];
#pragma unroll
        for (int df = 0; df < 4; df++) {
            f16x8 v0 = *(const f16x8*)&vbase[(size_t)(df * 16 + lr) * NTOK + kt + lg * 8];
            f16x8 v1 = *(const f16x8*)&vbase[(size_t)(df * 16 + lr) * NTOK + kt + 32 + lg * 8];
            o[df] = __builtin_amdgcn_mfma_f32_16x16x32_f16(pa0, v0, o[df], 0, 0, 0);
            o[df] = __builtin_amdgcn_mfma_f32_16x16x32_f16(pa1, v1, o[df], 0, 0, 0);
        }
    }

    // epilogue: normalize, add fp32 residual x, write fp32 y
#pragma unroll
    for (int r = 0; r < 4; r++) {
        const float inv = 1.0f / lrun[r];
        const int row = q0 + lg * 4 + r;
#pragma unroll
        for (int df = 0; df < 4; df++) {
            const size_t idx = (size_t)(b * NTOK + row) * 1024 + h * 64 + df * 16 + lr;
            y[idx] = o[df][r] * inv + x[idx];
        }
    }
}

extern "C" void kernel_launch(void* const* d_in, const int* in_sizes, int n_in,
                              void* d_out, int out_size, void* d_ws, size_t ws_size,
                              hipStream_t stream)
{
    const float* x   = (const float*)d_in[0];
    const float* Wq  = (const float*)d_in[1];
    const float* bq  = (const float*)d_in[2];
    const float* Wk  = (const float*)d_in[3];
    const float* bk  = (const float*)d_in[4];
    const float* Wv  = (const float*)d_in[5];
    const float* bv  = (const float*)d_in[6];
    const float* g1  = (const float*)d_in[7];
    const float* be1 = (const float*)d_in[8];
    const float* g2  = (const float*)d_in[9];
    const float* be2 = (const float*)d_in[10];
    const float* W1  = (const float*)d_in[11];
    const float* b1  = (const float*)d_in[12];
    const float* W2  = (const float*)d_in[13];
    const float* b2  = (const float*)d_in[14];

    char* ws = (char*)d_ws;
    unsigned short* WqkvT = (unsigned short*)ws;  ws += (size_t)3072 * 1024 * 2;
    unsigned short* W1T   = (unsigned short*)ws;  ws += (size_t)4096 * 1024 * 2;
    unsigned short* W2T   = (unsigned short*)ws;  ws += (size_t)1024 * 4096 * 2;
    float*          biasf = (float*)ws;           ws += (size_t)8192 * 4;
    unsigned short* h1    = (unsigned short*)ws;  ws += (size_t)MROWS * 1024 * 2;  // reused as h2
    unsigned short* qkv   = (unsigned short*)ws;  ws += (size_t)MROWS * 3072 * 2;
    unsigned short* vT    = (unsigned short*)ws;  ws += (size_t)32 * 64 * NTOK * 2;
    float*          y     = (float*)ws;           ws += (size_t)MROWS * 1024 * 4;
    unsigned short* act1  = (unsigned short*)ws;  ws += (size_t)MROWS * 4096 * 2;
    unsigned short* h2    = h1;  // h1 dead after QKV gemm

    bias_prep<<<32, 256, 0, stream>>>(bq, bk, bv, b1, b2, biasf);
    transpose_f2h<<<dim3(16, 16), 256, 0, stream>>>(Wq, 1024, WqkvT, 1024);
    transpose_f2h<<<dim3(16, 16), 256, 0, stream>>>(Wk, 1024, WqkvT + 1024 * 1024, 1024);
    transpose_f2h<<<dim3(16, 16), 256, 0, stream>>>(Wv, 1024, WqkvT + 2 * 1024 * 1024, 1024);
    transpose_f2h<<<dim3(64, 16), 256, 0, stream>>>(W1, 4096, W1T, 1024);
    transpose_f2h<<<dim3(16, 64), 256, 0, stream>>>(W2, 1024, W2T, 4096);

    ln_kernel<<<MROWS, 256, 0, stream>>>(x, g1, be1, h1);
    gemm_f16<0, unsigned short><<<dim3(24, 32), 256, 0, stream>>>(h1, 1024, WqkvT, 1024, biasf, nullptr, qkv, 3072, 1024);
    vtrans<<<dim3(32, 32), 256, 0, stream>>>(qkv, vT);
    attn_kernel<<<dim3(32, 32), 256, 0, stream>>>(qkv, vT, x, y);
    ln_kernel<<<MROWS, 256, 0, stream>>>(y, g2, be2, h2);
    gemm_f16<1, unsigned short><<<dim3(32, 32), 256, 0, stream>>>(h2, 1024, W1T, 1024, biasf + 3072, nullptr, act1, 4096, 1024);
    gemm_f16<2, float><<<dim3(8, 32), 256, 0, stream>>>(act1, 4096, W2T, 4096, biasf + 7168, y, (float*)d_out, 1024, 4096);
}

// Round 6
// 428.846 us; speedup vs baseline: 1.3764x; 1.3764x over previous
//
#include <hip/hip_runtime.h>
#include <math.h>

#define EMB 1024
#define HEADS 16
#define DH 64
#define DFF 4096
#define NTOK 2048
#define BATCH 2
#define MROWS 4096

typedef __attribute__((ext_vector_type(8))) _Float16 f16x8;
typedef __attribute__((ext_vector_type(4))) float floatx4;

typedef const __attribute__((address_space(1))) void gas_void;
typedef __attribute__((address_space(3))) void las_void;

__device__ __forceinline__ unsigned short f2h(float f) {
    union { _Float16 h; unsigned short u; } c; c.h = (_Float16)f; return c.u;
}
__device__ __forceinline__ float h2f(unsigned short u) {
    union { _Float16 h; unsigned short u; } c; c.u = u; return (float)c.h;
}

// ---------------- bias concat fp32: [bq|bk|bv | b1 | b2] = 3072+4096+1024 ----
__global__ __launch_bounds__(256) void bias_prep(
    const float* __restrict__ bq, const float* __restrict__ bk,
    const float* __restrict__ bv, const float* __restrict__ b1,
    const float* __restrict__ b2, float* __restrict__ out)
{
    int i = blockIdx.x * 256 + threadIdx.x;
    float v;
    if (i < 1024)      v = bq[i];
    else if (i < 2048) v = bk[i - 1024];
    else if (i < 3072) v = bv[i - 2048];
    else if (i < 7168) v = b1[i - 3072];
    else               v = b2[i - 7168];
    out[i] = v;
}

// ---------------- transpose fp32 -> fp16: out[c][r] = in[r][c], 64x64 tiles ----
__global__ __launch_bounds__(256) void transpose_f2h(
    const float* __restrict__ in, int ld_in,
    unsigned short* __restrict__ out, int ld_out)
{
    __shared__ unsigned short tile[64][72];
    const int t = threadIdx.x;
    const int r0 = blockIdx.y * 64, c0 = blockIdx.x * 64;
    const int rr = t >> 4, c4 = (t & 15) * 4;
#pragma unroll
    for (int p = 0; p < 4; p++) {
        float4 v = *(const float4*)&in[(size_t)(r0 + rr + p * 16) * ld_in + c0 + c4];
        tile[rr + p * 16][c4 + 0] = f2h(v.x);
        tile[rr + p * 16][c4 + 1] = f2h(v.y);
        tile[rr + p * 16][c4 + 2] = f2h(v.z);
        tile[rr + p * 16][c4 + 3] = f2h(v.w);
    }
    __syncthreads();
#pragma unroll
    for (int p = 0; p < 4; p++) {
        const int c = rr + p * 16;
        ushort4 v;
        v.x = tile[c4 + 0][c]; v.y = tile[c4 + 1][c];
        v.z = tile[c4 + 2][c]; v.w = tile[c4 + 3][c];
        *(ushort4*)&out[(size_t)(c0 + c) * ld_out + r0 + c4] = v;
    }
}

// ---------------- V transpose (fp16): vT[bh][d][n] = qkv[b*NTOK+n][2048+h*64+d] ----
__global__ __launch_bounds__(256) void vtrans(
    const unsigned short* __restrict__ qkv, unsigned short* __restrict__ vT)
{
    __shared__ unsigned short tile[64][72];
    const int t = threadIdx.x;
    const int n0 = blockIdx.x * 64;
    const int bh = blockIdx.y;
    const int b = bh >> 4, h = bh & 15;
    const int rr = t >> 4, c4 = (t & 15) * 4;
    const unsigned short* src = qkv + (size_t)b * NTOK * 3072 + 2048 + h * 64;
#pragma unroll
    for (int p = 0; p < 4; p++) {
        ushort4 v = *(const ushort4*)&src[(size_t)(n0 + rr + p * 16) * 3072 + c4];
        *(ushort4*)&tile[rr + p * 16][c4] = v;
    }
    __syncthreads();
    unsigned short* dst = vT + (size_t)bh * 64 * NTOK;
#pragma unroll
    for (int p = 0; p < 4; p++) {
        const int d = rr + p * 16;
        ushort4 v;
        v.x = tile[c4 + 0][d]; v.y = tile[c4 + 1][d];
        v.z = tile[c4 + 2][d]; v.w = tile[c4 + 3][d];
        *(ushort4*)&dst[(size_t)d * NTOK + n0 + c4] = v;
    }
}

// ---------------- LayerNorm: fp32 in -> fp16 out, rows of 1024 ----
__global__ __launch_bounds__(256) void ln_kernel(
    const float* __restrict__ in,
    const float* __restrict__ g,
    const float* __restrict__ be,
    unsigned short* __restrict__ out)
{
    const int row = blockIdx.x, t = threadIdx.x;
    const size_t base = (size_t)row * 1024 + t * 4;
    float4 xv = *(const float4*)&in[base];
    float v0 = xv.x, v1 = xv.y, v2 = xv.z, v3 = xv.w;
    float s = v0 + v1 + v2 + v3;
    float q = v0 * v0 + v1 * v1 + v2 * v2 + v3 * v3;
#pragma unroll
    for (int m = 1; m < 64; m <<= 1) { s += __shfl_xor(s, m, 64); q += __shfl_xor(q, m, 64); }
    __shared__ float red[8];
    if ((t & 63) == 0) { red[t >> 6] = s; red[4 + (t >> 6)] = q; }
    __syncthreads();
    s = red[0] + red[1] + red[2] + red[3];
    q = red[4] + red[5] + red[6] + red[7];
    const float mu = s * (1.f / 1024.f);
    const float var = q * (1.f / 1024.f) - mu * mu;
    const float rs = rsqrtf(var + 1e-6f);
    float4 gv = *(const float4*)&g[t * 4];
    float4 bv = *(const float4*)&be[t * 4];
    ushort4 ov;
    ov.x = f2h((v0 - mu) * rs * gv.x + bv.x);
    ov.y = f2h((v1 - mu) * rs * gv.y + bv.y);
    ov.z = f2h((v2 - mu) * rs * gv.z + bv.z);
    ov.w = f2h((v3 - mu) * rs * gv.w + bv.w);
    *(ushort4*)&out[base] = ov;
}

// ---------------- GEMM: C = A[M][K] @ Bt[N][K]^T + bias, epilogue EPI ----
// EPI 0: fp16 store. 1: exact GELU, fp16 store. 2: + fp32 resid, fp32 store.
// 128x128 tile, BK=64, 4 waves (2x2), 4x4 16x16x32-MFMA frags/wave (m97 structure)
template<int EPI, typename CT>
__global__ __launch_bounds__(256) void gemm_f16(
    const unsigned short* __restrict__ A, int lda,
    const unsigned short* __restrict__ Bt, int ldb,
    const float* __restrict__ bias,
    const float* __restrict__ resid,
    CT* __restrict__ C, int ldc, int K)
{
    __shared__ unsigned short As[128 * 64];
    __shared__ unsigned short Bs[128 * 64];
    const int t = threadIdx.x;
    const int l = t & 63, w = t >> 6;
    const int wr = w >> 1, wc = w & 1;
    const int lr = l & 15, lg = l >> 4;
    const int m0 = blockIdx.y * 128, n0 = blockIdx.x * 128;

    const int srow = t >> 3;        // 0..31
    const int scol = (t & 7) * 8;   // 0..56
    const unsigned short* ga0 = A + (size_t)(m0 + srow) * lda + scol;
    const unsigned short* gb0 = Bt + (size_t)(n0 + srow) * ldb + scol;
    const int ldsbase = w * 512;    // element offset, wave-uniform

    floatx4 acc[4][4];
#pragma unroll
    for (int a = 0; a < 4; a++)
#pragma unroll
        for (int b = 0; b < 4; b++) acc[a][b] = (floatx4){0.f, 0.f, 0.f, 0.f};

    for (int k0 = 0; k0 < K; k0 += 64) {
#pragma unroll
        for (int i = 0; i < 4; i++)
            __builtin_amdgcn_global_load_lds((gas_void*)(ga0 + (size_t)i * 32 * lda + k0),
                                             (las_void*)(As + i * 2048 + ldsbase), 16, 0, 0);
#pragma unroll
        for (int i = 0; i < 4; i++)
            __builtin_amdgcn_global_load_lds((gas_void*)(gb0 + (size_t)i * 32 * ldb + k0),
                                             (las_void*)(Bs + i * 2048 + ldsbase), 16, 0, 0);
        __syncthreads();
#pragma unroll
        for (int kf = 0; kf < 2; kf++) {
            f16x8 af[4], bfr[4];
#pragma unroll
            for (int a = 0; a < 4; a++)
                af[a] = *(const f16x8*)&As[(wr * 64 + a * 16 + lr) * 64 + kf * 32 + lg * 8];
#pragma unroll
            for (int b = 0; b < 4; b++)
                bfr[b] = *(const f16x8*)&Bs[(wc * 64 + b * 16 + lr) * 64 + kf * 32 + lg * 8];
#pragma unroll
            for (int a = 0; a < 4; a++)
#pragma unroll
                for (int b = 0; b < 4; b++)
                    acc[a][b] = __builtin_amdgcn_mfma_f32_16x16x32_f16(af[a], bfr[b], acc[a][b], 0, 0, 0);
        }
        __syncthreads();
    }

#pragma unroll
    for (int a = 0; a < 4; a++) {
        const int row0 = m0 + wr * 64 + a * 16 + lg * 4;
#pragma unroll
        for (int b = 0; b < 4; b++) {
            const int col = n0 + wc * 64 + b * 16 + lr;
            const float bs = bias[col];
#pragma unroll
            for (int r = 0; r < 4; r++) {
                float v = acc[a][b][r] + bs;
                if (EPI == 1) v = 0.5f * v * (1.0f + erff(v * 0.70710678118654752f));
                const size_t idx = (size_t)(row0 + r) * ldc + col;
                if (EPI == 2) v += resid[idx];
                if (sizeof(CT) == 2) C[idx] = (CT)f2h(v);
                else                 C[idx] = (CT)v;
            }
        }
    }
}

// ---------------- Flash attention v4 (no 1/sqrt(dh) scale!), residual fused ----
// grid (32 qblocks, 32 bh); block = 4 waves x 16 q-rows = 64 rows; KVBLK = 64.
// K/V tiles LDS-staged via global_load_lds (XOR-swizzled source, swizzled read).
// Swapped QK^T: s = mfma(K, Q) so each lane holds all tile-scores for one q-row
// -> softmax reduce = per-lane fmax tree + 2 shfl_xor (no deep shfl chains).
__global__ __launch_bounds__(256, 4) void attn_kernel(
    const unsigned short* __restrict__ qkv,
    const unsigned short* __restrict__ vT,
    const float* __restrict__ x,
    float* __restrict__ y)
{
    __shared__ __align__(16) unsigned short Ks[64 * 64];    // [key][dh] 128B rows, swizzled
    __shared__ __align__(16) unsigned short Vs[64 * 64];    // [d][key] 128B rows, swizzled
    __shared__ __align__(16) unsigned short P[4][16 * 72];  // per-wave [q][key], 144B rows
    const int t = threadIdx.x;
    const int l = t & 63, w = t >> 6;
    const int lr = l & 15, lg = l >> 4;
    const int qb = blockIdx.x, bh = blockIdx.y;
    const int b = bh >> 4, h = bh & 15;
    const int q0 = qb * 64 + w * 16;   // this wave's 16 q-rows

    const unsigned short* qbase = qkv + (size_t)b * NTOK * 3072 + h * 64;
    const unsigned short* kbase = qbase + 1024;
    const unsigned short* vbase = vT + (size_t)bh * 64 * NTOK;

    // staging map: pass p row = p*32 + (t>>3); col slot = (t&7)*16 bytes
    const int rr = t >> 3;                       // 0..31
    const int ce = (((t & 7) * 16) ^ ((rr & 7) << 4)) >> 1;  // swizzled src col (elements)
    const int ldsoff = rr * 64 + (t & 7) * 8;    // linear dest (elements), +p*2048

    // Q fragments (loop-invariant): B-operand rows = q
    f16x8 qf[2];
#pragma unroll
    for (int kf = 0; kf < 2; kf++)
        qf[kf] = *(const f16x8*)&qbase[(size_t)(q0 + lr) * 3072 + kf * 32 + lg * 8];

    floatx4 o[4];
    float mrun = -1e30f, lrun = 0.f;   // stats for q = q0 + lr
#pragma unroll
    for (int df = 0; df < 4; df++) o[df] = (floatx4){0.f, 0.f, 0.f, 0.f};

    const int swz = (lr & 7) << 4;  // read-side XOR (row&7 == lr&7 for all frag rows)

    for (int kt = 0; kt < NTOK; kt += 64) {
        // ---- stage K and V tiles (2 passes each) ----
#pragma unroll
        for (int p = 0; p < 2; p++) {
            __builtin_amdgcn_global_load_lds(
                (gas_void*)(kbase + (size_t)(kt + p * 32 + rr) * 3072 + ce),
                (las_void*)(Ks + p * 2048 + ldsoff), 16, 0, 0);
            __builtin_amdgcn_global_load_lds(
                (gas_void*)(vbase + (size_t)(p * 32 + rr) * NTOK + kt + ce),
                (las_void*)(Vs + p * 2048 + ldsoff), 16, 0, 0);
        }
        __syncthreads();

        // ---- QK^T (swapped): s[n][r] = score(key = kt+n*16+lg*4+r, q = q0+lr) ----
        floatx4 s[4];
#pragma unroll
        for (int n = 0; n < 4; n++) {
            const int krow = n * 16 + lr;
            f16x8 ka0 = *(const f16x8*)((const char*)Ks + krow * 128 + ((lg * 16) ^ swz));
            f16x8 ka1 = *(const f16x8*)((const char*)Ks + krow * 128 + ((64 + lg * 16) ^ swz));
            s[n] = (floatx4){0.f, 0.f, 0.f, 0.f};
            s[n] = __builtin_amdgcn_mfma_f32_16x16x32_f16(ka0, qf[0], s[n], 0, 0, 0);
            s[n] = __builtin_amdgcn_mfma_f32_16x16x32_f16(ka1, qf[1], s[n], 0, 0, 0);
        }

        // ---- online softmax for q = q0+lr (all 16 values lane-local) ----
        float pm = s[0][0];
#pragma unroll
        for (int n = 0; n < 4; n++)
#pragma unroll
            for (int r = 0; r < 4; r++) pm = fmaxf(pm, s[n][r]);
        pm = fmaxf(pm, __shfl_xor(pm, 16, 64));
        pm = fmaxf(pm, __shfl_xor(pm, 32, 64));
        const float nm = fmaxf(mrun, pm);
        const float corr = __expf(mrun - nm);
        mrun = nm;
        float ts = 0.f;
#pragma unroll
        for (int n = 0; n < 4; n++)
#pragma unroll
            for (int r = 0; r < 4; r++) {
                float e = __expf(s[n][r] - nm);
                s[n][r] = e;
                ts += e;
            }
        ts += __shfl_xor(ts, 16, 64);
        ts += __shfl_xor(ts, 32, 64);
        lrun = lrun * corr + ts;

        // rescale O (its q-index is lg*4+r -> broadcast corr from lane lg*4+r)
        float co[4];
#pragma unroll
        for (int r = 0; r < 4; r++) co[r] = __shfl(corr, lg * 4 + r, 64);
#pragma unroll
        for (int df = 0; df < 4; df++)
#pragma unroll
            for (int r = 0; r < 4; r++) o[df][r] *= co[r];

        // ---- write P[q=lr][key] to wave-private LDS (4 x b64) ----
#pragma unroll
        for (int n = 0; n < 4; n++) {
            ushort4 pw;
            pw.x = f2h(s[n][0]); pw.y = f2h(s[n][1]);
            pw.z = f2h(s[n][2]); pw.w = f2h(s[n][3]);
            *(ushort4*)((char*)P[w] + lr * 144 + n * 32 + lg * 8) = pw;
        }

        // ---- PV: O[q][d] += P[q][key] * vT[d][key] ----
#pragma unroll
        for (int c = 0; c < 2; c++) {
            f16x8 pa = *(const f16x8*)((const char*)P[w] + lr * 144 + c * 64 + lg * 16);
#pragma unroll
            for (int df = 0; df < 4; df++) {
                const int vrow = df * 16 + lr;
                f16x8 vb = *(const f16x8*)((const char*)Vs + vrow * 128 + ((c * 64 + lg * 16) ^ swz));
                o[df] = __builtin_amdgcn_mfma_f32_16x16x32_f16(pa, vb, o[df], 0, 0, 0);
            }
        }
        __syncthreads();
    }

    // epilogue: normalize (stats live in lane lg*4+r), add fp32 residual, store
#pragma unroll
    for (int r = 0; r < 4; r++) {
        const float inv = 1.0f / __shfl(lrun, lg * 4 + r, 64);
        const int row = q0 + lg * 4 + r;
#pragma unroll
        for (int df = 0; df < 4; df++) {
            const size_t idx = (size_t)(b * NTOK + row) * 1024 + h * 64 + df * 16 + lr;
            y[idx] = o[df][r] * inv + x[idx];
        }
    }
}

extern "C" void kernel_launch(void* const* d_in, const int* in_sizes, int n_in,
                              void* d_out, int out_size, void* d_ws, size_t ws_size,
                              hipStream_t stream)
{
    const float* x   = (const float*)d_in[0];
    const float* Wq  = (const float*)d_in[1];
    const float* bq  = (const float*)d_in[2];
    const float* Wk  = (const float*)d_in[3];
    const float* bk  = (const float*)d_in[4];
    const float* Wv  = (const float*)d_in[5];
    const float* bv  = (const float*)d_in[6];
    const float* g1  = (const float*)d_in[7];
    const float* be1 = (const float*)d_in[8];
    const float* g2  = (const float*)d_in[9];
    const float* be2 = (const float*)d_in[10];
    const float* W1  = (const float*)d_in[11];
    const float* b1  = (const float*)d_in[12];
    const float* W2  = (const float*)d_in[13];
    const float* b2  = (const float*)d_in[14];

    char* ws = (char*)d_ws;
    unsigned short* WqkvT = (unsigned short*)ws;  ws += (size_t)3072 * 1024 * 2;
    unsigned short* W1T   = (unsigned short*)ws;  ws += (size_t)4096 * 1024 * 2;
    unsigned short* W2T   = (unsigned short*)ws;  ws += (size_t)1024 * 4096 * 2;
    float*          biasf = (float*)ws;           ws += (size_t)8192 * 4;
    unsigned short* h1    = (unsigned short*)ws;  ws += (size_t)MROWS * 1024 * 2;  // reused as h2
    unsigned short* qkv   = (unsigned short*)ws;  ws += (size_t)MROWS * 3072 * 2;
    unsigned short* vT    = (unsigned short*)ws;  ws += (size_t)32 * 64 * NTOK * 2;
    float*          y     = (float*)ws;           ws += (size_t)MROWS * 1024 * 4;
    unsigned short* act1  = (unsigned short*)ws;  ws += (size_t)MROWS * 4096 * 2;
    unsigned short* h2    = h1;  // h1 dead after QKV gemm

    bias_prep<<<32, 256, 0, stream>>>(bq, bk, bv, b1, b2, biasf);
    transpose_f2h<<<dim3(16, 16), 256, 0, stream>>>(Wq, 1024, WqkvT, 1024);
    transpose_f2h<<<dim3(16, 16), 256, 0, stream>>>(Wk, 1024, WqkvT + 1024 * 1024, 1024);
    transpose_f2h<<<dim3(16, 16), 256, 0, stream>>>(Wv, 1024, WqkvT + 2 * 1024 * 1024, 1024);
    transpose_f2h<<<dim3(64, 16), 256, 0, stream>>>(W1, 4096, W1T, 1024);
    transpose_f2h<<<dim3(16, 64), 256, 0, stream>>>(W2, 1024, W2T, 4096);

    ln_kernel<<<MROWS, 256, 0, stream>>>(x, g1, be1, h1);
    gemm_f16<0, unsigned short><<<dim3(24, 32), 256, 0, stream>>>(h1, 1024, WqkvT, 1024, biasf, nullptr, qkv, 3072, 1024);
    vtrans<<<dim3(32, 32), 256, 0, stream>>>(qkv, vT);
    attn_kernel<<<dim3(32, 32), 256, 0, stream>>>(qkv, vT, x, y);
    ln_kernel<<<MROWS, 256, 0, stream>>>(y, g2, be2, h2);
    gemm_f16<1, unsigned short><<<dim3(32, 32), 256, 0, stream>>>(h2, 1024, W1T, 1024, biasf + 3072, nullptr, act1, 4096, 1024);
    gemm_f16<2, float><<<dim3(8, 32), 256, 0, stream>>>(act1, 4096, W2T, 4096, biasf + 7168, y, (float*)d_out, 1024, 4096);
}

// Round 8
// 420.149 us; speedup vs baseline: 1.4048x; 1.0207x over previous
//
#include <hip/hip_runtime.h>
#include <math.h>

#define EMB 1024
#define HEADS 16
#define DH 64
#define DFF 4096
#define NTOK 2048
#define BATCH 2
#define MROWS 4096

typedef __attribute__((ext_vector_type(8))) _Float16 f16x8;
typedef __attribute__((ext_vector_type(4))) float floatx4;

typedef const __attribute__((address_space(1))) void gas_void;
typedef __attribute__((address_space(3))) void las_void;

__device__ __forceinline__ unsigned short f2h(float f) {
    union { _Float16 h; unsigned short u; } c; c.h = (_Float16)f; return c.u;
}
__device__ __forceinline__ float h2f(unsigned short u) {
    union { _Float16 h; unsigned short u; } c; c.u = u; return (float)c.h;
}

// ---------------- bias concat fp32: [bq|bk|bv | b1 | b2] = 3072+4096+1024 ----
__global__ __launch_bounds__(256) void bias_prep(
    const float* __restrict__ bq, const float* __restrict__ bk,
    const float* __restrict__ bv, const float* __restrict__ b1,
    const float* __restrict__ b2, float* __restrict__ out)
{
    int i = blockIdx.x * 256 + threadIdx.x;
    float v;
    if (i < 1024)      v = bq[i];
    else if (i < 2048) v = bk[i - 1024];
    else if (i < 3072) v = bv[i - 2048];
    else if (i < 7168) v = b1[i - 3072];
    else               v = b2[i - 7168];
    out[i] = v;
}

// ---------------- transpose fp32 -> fp16: out[c][r] = in[r][c], 64x64 tiles ----
__global__ __launch_bounds__(256) void transpose_f2h(
    const float* __restrict__ in, int ld_in,
    unsigned short* __restrict__ out, int ld_out)
{
    __shared__ unsigned short tile[64][72];
    const int t = threadIdx.x;
    const int r0 = blockIdx.y * 64, c0 = blockIdx.x * 64;
    const int rr = t >> 4, c4 = (t & 15) * 4;
#pragma unroll
    for (int p = 0; p < 4; p++) {
        float4 v = *(const float4*)&in[(size_t)(r0 + rr + p * 16) * ld_in + c0 + c4];
        tile[rr + p * 16][c4 + 0] = f2h(v.x);
        tile[rr + p * 16][c4 + 1] = f2h(v.y);
        tile[rr + p * 16][c4 + 2] = f2h(v.z);
        tile[rr + p * 16][c4 + 3] = f2h(v.w);
    }
    __syncthreads();
#pragma unroll
    for (int p = 0; p < 4; p++) {
        const int c = rr + p * 16;
        ushort4 v;
        v.x = tile[c4 + 0][c]; v.y = tile[c4 + 1][c];
        v.z = tile[c4 + 2][c]; v.w = tile[c4 + 3][c];
        *(ushort4*)&out[(size_t)(c0 + c) * ld_out + r0 + c4] = v;
    }
}

// ---------------- V transpose (fp16): vT[bh][d][n] = qkv[b*NTOK+n][2048+h*64+d] ----
__global__ __launch_bounds__(256) void vtrans(
    const unsigned short* __restrict__ qkv, unsigned short* __restrict__ vT)
{
    __shared__ unsigned short tile[64][72];
    const int t = threadIdx.x;
    const int n0 = blockIdx.x * 64;
    const int bh = blockIdx.y;
    const int b = bh >> 4, h = bh & 15;
    const int rr = t >> 4, c4 = (t & 15) * 4;
    const unsigned short* src = qkv + (size_t)b * NTOK * 3072 + 2048 + h * 64;
#pragma unroll
    for (int p = 0; p < 4; p++) {
        ushort4 v = *(const ushort4*)&src[(size_t)(n0 + rr + p * 16) * 3072 + c4];
        *(ushort4*)&tile[rr + p * 16][c4] = v;
    }
    __syncthreads();
    unsigned short* dst = vT + (size_t)bh * 64 * NTOK;
#pragma unroll
    for (int p = 0; p < 4; p++) {
        const int d = rr + p * 16;
        ushort4 v;
        v.x = tile[c4 + 0][d]; v.y = tile[c4 + 1][d];
        v.z = tile[c4 + 2][d]; v.w = tile[c4 + 3][d];
        *(ushort4*)&dst[(size_t)d * NTOK + n0 + c4] = v;
    }
}

// ---------------- LayerNorm: fp32 in -> fp16 out, rows of 1024 ----
__global__ __launch_bounds__(256) void ln_kernel(
    const float* __restrict__ in,
    const float* __restrict__ g,
    const float* __restrict__ be,
    unsigned short* __restrict__ out)
{
    const int row = blockIdx.x, t = threadIdx.x;
    const size_t base = (size_t)row * 1024 + t * 4;
    float4 xv = *(const float4*)&in[base];
    float v0 = xv.x, v1 = xv.y, v2 = xv.z, v3 = xv.w;
    float s = v0 + v1 + v2 + v3;
    float q = v0 * v0 + v1 * v1 + v2 * v2 + v3 * v3;
#pragma unroll
    for (int m = 1; m < 64; m <<= 1) { s += __shfl_xor(s, m, 64); q += __shfl_xor(q, m, 64); }
    __shared__ float red[8];
    if ((t & 63) == 0) { red[t >> 6] = s; red[4 + (t >> 6)] = q; }
    __syncthreads();
    s = red[0] + red[1] + red[2] + red[3];
    q = red[4] + red[5] + red[6] + red[7];
    const float mu = s * (1.f / 1024.f);
    const float var = q * (1.f / 1024.f) - mu * mu;
    const float rs = rsqrtf(var + 1e-6f);
    float4 gv = *(const float4*)&g[t * 4];
    float4 bv = *(const float4*)&be[t * 4];
    ushort4 ov;
    ov.x = f2h((v0 - mu) * rs * gv.x + bv.x);
    ov.y = f2h((v1 - mu) * rs * gv.y + bv.y);
    ov.z = f2h((v2 - mu) * rs * gv.z + bv.z);
    ov.w = f2h((v3 - mu) * rs * gv.w + bv.w);
    *(ushort4*)&out[base] = ov;
}

// ---------------- GEMM (2-phase double-buffered): C = A @ Bt^T + bias ----
// EPI 0: fp16 store. 1: exact GELU, fp16 store. 2: + fp32 resid, fp32 store.
// 128x128 tile, BK=64, 4 waves (2x2), 4x4 16x16x32-MFMA frags/wave.
// Next K-tile staged via global_load_lds BEFORE current tile's MFMA; the
// compiler's vmcnt(0) drain before s_barrier then overlaps the MFMA cluster.
template<int EPI, typename CT>
__global__ __launch_bounds__(256, 2) void gemm_f16(
    const unsigned short* __restrict__ A, int lda,
    const unsigned short* __restrict__ Bt, int ldb,
    const float* __restrict__ bias,
    const float* __restrict__ resid,
    CT* __restrict__ C, int ldc, int K)
{
    __shared__ unsigned short As[2][128 * 64];
    __shared__ unsigned short Bs[2][128 * 64];
    const int t = threadIdx.x;
    const int l = t & 63, w = t >> 6;
    const int wr = w >> 1, wc = w & 1;
    const int lr = l & 15, lg = l >> 4;
    const int m0 = blockIdx.y * 128, n0 = blockIdx.x * 128;

    const int srow = t >> 3;        // 0..31
    const int scol = (t & 7) * 8;   // 0..56
    const unsigned short* ga0 = A + (size_t)(m0 + srow) * lda + scol;
    const unsigned short* gb0 = Bt + (size_t)(n0 + srow) * ldb + scol;
    const int ldsbase = w * 512;    // element offset, wave-uniform

    floatx4 acc[4][4];
#pragma unroll
    for (int a = 0; a < 4; a++)
#pragma unroll
        for (int b = 0; b < 4; b++) acc[a][b] = (floatx4){0.f, 0.f, 0.f, 0.f};

    auto stage = [&](int buf, int k0) {
#pragma unroll
        for (int i = 0; i < 4; i++)
            __builtin_amdgcn_global_load_lds((gas_void*)(ga0 + (size_t)i * 32 * lda + k0),
                                             (las_void*)(As[buf] + i * 2048 + ldsbase), 16, 0, 0);
#pragma unroll
        for (int i = 0; i < 4; i++)
            __builtin_amdgcn_global_load_lds((gas_void*)(gb0 + (size_t)i * 32 * ldb + k0),
                                             (las_void*)(Bs[buf] + i * 2048 + ldsbase), 16, 0, 0);
    };

    stage(0, 0);
    __syncthreads();

    const int nt = K >> 6;
    for (int tk = 0; tk < nt; tk++) {
        if (tk + 1 < nt) stage((tk + 1) & 1, (tk + 1) << 6);
        const unsigned short* as = As[tk & 1];
        const unsigned short* bs = Bs[tk & 1];
#pragma unroll
        for (int kf = 0; kf < 2; kf++) {
            f16x8 af[4], bfr[4];
#pragma unroll
            for (int a = 0; a < 4; a++)
                af[a] = *(const f16x8*)&as[(wr * 64 + a * 16 + lr) * 64 + kf * 32 + lg * 8];
#pragma unroll
            for (int b = 0; b < 4; b++)
                bfr[b] = *(const f16x8*)&bs[(wc * 64 + b * 16 + lr) * 64 + kf * 32 + lg * 8];
#pragma unroll
            for (int a = 0; a < 4; a++)
#pragma unroll
                for (int b = 0; b < 4; b++)
                    acc[a][b] = __builtin_amdgcn_mfma_f32_16x16x32_f16(af[a], bfr[b], acc[a][b], 0, 0, 0);
        }
        __syncthreads();   // drains vmcnt(0) AFTER compute: next-tile loads landed
    }

#pragma unroll
    for (int a = 0; a < 4; a++) {
        const int row0 = m0 + wr * 64 + a * 16 + lg * 4;
#pragma unroll
        for (int b = 0; b < 4; b++) {
            const int col = n0 + wc * 64 + b * 16 + lr;
            const float bs = bias[col];
#pragma unroll
            for (int r = 0; r < 4; r++) {
                float v = acc[a][b][r] + bs;
                if (EPI == 1) v = 0.5f * v * (1.0f + erff(v * 0.70710678118654752f));
                const size_t idx = (size_t)(row0 + r) * ldc + col;
                if (EPI == 2) v += resid[idx];
                if (sizeof(CT) == 2) C[idx] = (CT)f2h(v);
                else                 C[idx] = (CT)v;
            }
        }
    }
}

// ---------------- Flash attention v4 (no 1/sqrt(dh) scale!), residual fused ----
// grid (32 qblocks, 32 bh); block = 4 waves x 16 q-rows = 64 rows; KVBLK = 64.
// K/V tiles LDS-staged via global_load_lds (XOR-swizzled source, swizzled read).
// Swapped QK^T: s = mfma(K, Q) so each lane holds all tile-scores for one q-row.
__global__ __launch_bounds__(256, 4) void attn_kernel(
    const unsigned short* __restrict__ qkv,
    const unsigned short* __restrict__ vT,
    const float* __restrict__ x,
    float* __restrict__ y)
{
    __shared__ __align__(16) unsigned short Ks[64 * 64];    // [key][dh] 128B rows, swizzled
    __shared__ __align__(16) unsigned short Vs[64 * 64];    // [d][key] 128B rows, swizzled
    __shared__ __align__(16) unsigned short P[4][16 * 72];  // per-wave [q][key], 144B rows
    const int t = threadIdx.x;
    const int l = t & 63, w = t >> 6;
    const int lr = l & 15, lg = l >> 4;
    const int qb = blockIdx.x, bh = blockIdx.y;
    const int b = bh >> 4, h = bh & 15;
    const int q0 = qb * 64 + w * 16;   // this wave's 16 q-rows

    const unsigned short* qbase = qkv + (size_t)b * NTOK * 3072 + h * 64;
    const unsigned short* kbase = qbase + 1024;
    const unsigned short* vbase = vT + (size_t)bh * 64 * NTOK;

    // staging map: pass p row = p*32 + (t>>3); col slot = (t&7)*16 bytes
    const int rr = t >> 3;                       // 0..31
    const int ce = (((t & 7) * 16) ^ ((rr & 7) << 4)) >> 1;  // swizzled src col (elements)
    const int ldsoff = rr * 64 + (t & 7) * 8;    // linear dest (elements), +p*2048

    // Q fragments (loop-invariant): B-operand rows = q
    f16x8 qf[2];
#pragma unroll
    for (int kf = 0; kf < 2; kf++)
        qf[kf] = *(const f16x8*)&qbase[(size_t)(q0 + lr) * 3072 + kf * 32 + lg * 8];

    floatx4 o[4];
    float mrun = -1e30f, lrun = 0.f;   // stats for q = q0 + lr
#pragma unroll
    for (int df = 0; df < 4; df++) o[df] = (floatx4){0.f, 0.f, 0.f, 0.f};

    const int swz = (lr & 7) << 4;  // read-side XOR (row&7 == lr&7 for all frag rows)

    for (int kt = 0; kt < NTOK; kt += 64) {
        // ---- stage K and V tiles (2 passes each) ----
#pragma unroll
        for (int p = 0; p < 2; p++) {
            __builtin_amdgcn_global_load_lds(
                (gas_void*)(kbase + (size_t)(kt + p * 32 + rr) * 3072 + ce),
                (las_void*)(Ks + p * 2048 + ldsoff), 16, 0, 0);
            __builtin_amdgcn_global_load_lds(
                (gas_void*)(vbase + (size_t)(p * 32 + rr) * NTOK + kt + ce),
                (las_void*)(Vs + p * 2048 + ldsoff), 16, 0, 0);
        }
        __syncthreads();

        // ---- QK^T (swapped): s[n][r] = score(key = kt+n*16+lg*4+r, q = q0+lr) ----
        floatx4 s[4];
#pragma unroll
        for (int n = 0; n < 4; n++) {
            const int krow = n * 16 + lr;
            f16x8 ka0 = *(const f16x8*)((const char*)Ks + krow * 128 + ((lg * 16) ^ swz));
            f16x8 ka1 = *(const f16x8*)((const char*)Ks + krow * 128 + ((64 + lg * 16) ^ swz));
            s[n] = (floatx4){0.f, 0.f, 0.f, 0.f};
            s[n] = __builtin_amdgcn_mfma_f32_16x16x32_f16(ka0, qf[0], s[n], 0, 0, 0);
            s[n] = __builtin_amdgcn_mfma_f32_16x16x32_f16(ka1, qf[1], s[n], 0, 0, 0);
        }

        // ---- online softmax for q = q0+lr (all 16 values lane-local) ----
        float pm = s[0][0];
#pragma unroll
        for (int n = 0; n < 4; n++)
#pragma unroll
            for (int r = 0; r < 4; r++) pm = fmaxf(pm, s[n][r]);
        pm = fmaxf(pm, __shfl_xor(pm, 16, 64));
        pm = fmaxf(pm, __shfl_xor(pm, 32, 64));
        const float nm = fmaxf(mrun, pm);
        const float corr = __expf(mrun - nm);
        mrun = nm;
        float ts = 0.f;
#pragma unroll
        for (int n = 0; n < 4; n++)
#pragma unroll
            for (int r = 0; r < 4; r++) {
                float e = __expf(s[n][r] - nm);
                s[n][r] = e;
                ts += e;
            }
        ts += __shfl_xor(ts, 16, 64);
        ts += __shfl_xor(ts, 32, 64);
        lrun = lrun * corr + ts;

        // rescale O (its q-index is lg*4+r -> broadcast corr from lane lg*4+r)
        float co[4];
#pragma unroll
        for (int r = 0; r < 4; r++) co[r] = __shfl(corr, lg * 4 + r, 64);
#pragma unroll
        for (int df = 0; df < 4; df++)
#pragma unroll
            for (int r = 0; r < 4; r++) o[df][r] *= co[r];

        // ---- write P[q=lr][key] to wave-private LDS (4 x b64) ----
#pragma unroll
        for (int n = 0; n < 4; n++) {
            ushort4 pw;
            pw.x = f2h(s[n][0]); pw.y = f2h(s[n][1]);
            pw.z = f2h(s[n][2]); pw.w = f2h(s[n][3]);
            *(ushort4*)((char*)P[w] + lr * 144 + n * 32 + lg * 8) = pw;
        }

        // ---- PV: O[q][d] += P[q][key] * vT[d][key] ----
#pragma unroll
        for (int c = 0; c < 2; c++) {
            f16x8 pa = *(const f16x8*)((const char*)P[w] + lr * 144 + c * 64 + lg * 16);
#pragma unroll
            for (int df = 0; df < 4; df++) {
                const int vrow = df * 16 + lr;
                f16x8 vb = *(const f16x8*)((const char*)Vs + vrow * 128 + ((c * 64 + lg * 16) ^ swz));
                o[df] = __builtin_amdgcn_mfma_f32_16x16x32_f16(pa, vb, o[df], 0, 0, 0);
            }
        }
        __syncthreads();
    }

    // epilogue: normalize (stats live in lane lg*4+r), add fp32 residual, store
#pragma unroll
    for (int r = 0; r < 4; r++) {
        const float inv = 1.0f / __shfl(lrun, lg * 4 + r, 64);
        const int row = q0 + lg * 4 + r;
#pragma unroll
        for (int df = 0; df < 4; df++) {
            const size_t idx = (size_t)(b * NTOK + row) * 1024 + h * 64 + df * 16 + lr;
            y[idx] = o[df][r] * inv + x[idx];
        }
    }
}

extern "C" void kernel_launch(void* const* d_in, const int* in_sizes, int n_in,
                              void* d_out, int out_size, void* d_ws, size_t ws_size,
                              hipStream_t stream)
{
    const float* x   = (const float*)d_in[0];
    const float* Wq  = (const float*)d_in[1];
    const float* bq  = (const float*)d_in[2];
    const float* Wk  = (const float*)d_in[3];
    const float* bk  = (const float*)d_in[4];
    const float* Wv  = (const float*)d_in[5];
    const float* bv  = (const float*)d_in[6];
    const float* g1  = (const float*)d_in[7];
    const float* be1 = (const float*)d_in[8];
    const float* g2  = (const float*)d_in[9];
    const float* be2 = (const float*)d_in[10];
    const float* W1  = (const float*)d_in[11];
    const float* b1  = (const float*)d_in[12];
    const float* W2  = (const float*)d_in[13];
    const float* b2  = (const float*)d_in[14];

    char* ws = (char*)d_ws;
    unsigned short* WqkvT = (unsigned short*)ws;  ws += (size_t)3072 * 1024 * 2;
    unsigned short* W1T   = (unsigned short*)ws;  ws += (size_t)4096 * 1024 * 2;
    unsigned short* W2T   = (unsigned short*)ws;  ws += (size_t)1024 * 4096 * 2;
    float*          biasf = (float*)ws;           ws += (size_t)8192 * 4;
    unsigned short* h1    = (unsigned short*)ws;  ws += (size_t)MROWS * 1024 * 2;  // reused as h2
    unsigned short* qkv   = (unsigned short*)ws;  ws += (size_t)MROWS * 3072 * 2;
    unsigned short* vT    = (unsigned short*)ws;  ws += (size_t)32 * 64 * NTOK * 2;
    float*          y     = (float*)ws;           ws += (size_t)MROWS * 1024 * 4;
    unsigned short* act1  = (unsigned short*)ws;  ws += (size_t)MROWS * 4096 * 2;
    unsigned short* h2    = h1;  // h1 dead after QKV gemm

    bias_prep<<<32, 256, 0, stream>>>(bq, bk, bv, b1, b2, biasf);
    transpose_f2h<<<dim3(16, 16), 256, 0, stream>>>(Wq, 1024, WqkvT, 1024);
    transpose_f2h<<<dim3(16, 16), 256, 0, stream>>>(Wk, 1024, WqkvT + 1024 * 1024, 1024);
    transpose_f2h<<<dim3(16, 16), 256, 0, stream>>>(Wv, 1024, WqkvT + 2 * 1024 * 1024, 1024);
    transpose_f2h<<<dim3(64, 16), 256, 0, stream>>>(W1, 4096, W1T, 1024);
    transpose_f2h<<<dim3(16, 64), 256, 0, stream>>>(W2, 1024, W2T, 4096);

    ln_kernel<<<MROWS, 256, 0, stream>>>(x, g1, be1, h1);
    gemm_f16<0, unsigned short><<<dim3(24, 32), 256, 0, stream>>>(h1, 1024, WqkvT, 1024, biasf, nullptr, qkv, 3072, 1024);
    vtrans<<<dim3(32, 32), 256, 0, stream>>>(qkv, vT);
    attn_kernel<<<dim3(32, 32), 256, 0, stream>>>(qkv, vT, x, y);
    ln_kernel<<<MROWS, 256, 0, stream>>>(y, g2, be2, h2);
    gemm_f16<1, unsigned short><<<dim3(32, 32), 256, 0, stream>>>(h2, 1024, W1T, 1024, biasf + 3072, nullptr, act1, 4096, 1024);
    gemm_f16<2, float><<<dim3(8, 32), 256, 0, stream>>>(act1, 4096, W2T, 4096, biasf + 7168, y, (float*)d_out, 1024, 4096);
}